// Round 1
// baseline (397.360 us; speedup 1.0000x reference)
//
#include <hip/hip_runtime.h>
#include <hip/hip_bf16.h>

typedef float  f32x4  __attribute__((ext_vector_type(4)));
typedef short  bf16x8 __attribute__((ext_vector_type(8)));
typedef unsigned int   u32;
typedef unsigned short u16;

#define TOKENS 8192
#define NDIM   4096
#define KDIM   4096

__device__ __forceinline__ u16 f2bf(float f) {
  u32 u = __float_as_uint(f);
  u += 0x7fffu + ((u >> 16) & 1u);   // round-to-nearest-even
  return (u16)(u >> 16);
}

// ---------------------------------------------------------------------------
// Kernel 1: FWHT over each row of x (4096 f32), orthonormal (scale 1/64),
// output bf16. One wave (64 lanes) per row; 64 f32 per lane in registers.
// Bits 0..5 of the index: in-register butterflies. Bits 6..11: shfl_xor.
// ---------------------------------------------------------------------------
__global__ __launch_bounds__(64)
void fwht_rows(const float* __restrict__ x, u16* __restrict__ xh) {
  const int row = blockIdx.x;
  const int l   = threadIdx.x;

  const float4* xv = reinterpret_cast<const float4*>(x + (size_t)row * KDIM) + l * 16;
  float v[64];
#pragma unroll
  for (int j = 0; j < 16; ++j) {
    float4 f = xv[j];
    v[4*j+0] = f.x; v[4*j+1] = f.y; v[4*j+2] = f.z; v[4*j+3] = f.w;
  }

  // in-register stages: bits 0..5 (h = 1..32)
#pragma unroll
  for (int h = 1; h < 64; h <<= 1) {
#pragma unroll
    for (int j = 0; j < 64; ++j) {
      if ((j & h) == 0) {
        float a = v[j], b = v[j + h];
        v[j] = a + b; v[j + h] = a - b;
      }
    }
  }

  // cross-lane stages: bits 6..11 (lane xor masks 1..32)
#pragma unroll
  for (int m = 1; m < 64; m <<= 1) {
    const bool up = (l & m) != 0;
#pragma unroll
    for (int j = 0; j < 64; ++j) {
      float p = __shfl_xor(v[j], m, 64);
      v[j] = up ? (p - v[j]) : (v[j] + p);
    }
  }

  // scale by 1/sqrt(4096) and store bf16, 16B per store
  u16* orow = xh + (size_t)row * KDIM + l * 64;
#pragma unroll
  for (int g = 0; g < 8; ++g) {
    uint4 pk;
    pk.x = (u32)f2bf(v[g*8+0] * 0.015625f) | ((u32)f2bf(v[g*8+1] * 0.015625f) << 16);
    pk.y = (u32)f2bf(v[g*8+2] * 0.015625f) | ((u32)f2bf(v[g*8+3] * 0.015625f) << 16);
    pk.z = (u32)f2bf(v[g*8+4] * 0.015625f) | ((u32)f2bf(v[g*8+5] * 0.015625f) << 16);
    pk.w = (u32)f2bf(v[g*8+6] * 0.015625f) | ((u32)f2bf(v[g*8+7] * 0.015625f) << 16);
    *reinterpret_cast<uint4*>(orow + g * 8) = pk;
  }
}

// ---------------------------------------------------------------------------
// Kernel 2: W[o][k] = bf16((float)Q[o][k] * s[o]).  8 elems/thread.
// ---------------------------------------------------------------------------
__global__ __launch_bounds__(256)
void wconv(const int* __restrict__ Q, const float* __restrict__ s,
           u16* __restrict__ W) {
  const size_t idx = ((size_t)blockIdx.x * 256 + threadIdx.x) * 8;
  const float sv = s[idx >> 12];
  int4 q0 = *reinterpret_cast<const int4*>(Q + idx);
  int4 q1 = *reinterpret_cast<const int4*>(Q + idx + 4);
  uint4 pk;
  pk.x = (u32)f2bf((float)q0.x * sv) | ((u32)f2bf((float)q0.y * sv) << 16);
  pk.y = (u32)f2bf((float)q0.z * sv) | ((u32)f2bf((float)q0.w * sv) << 16);
  pk.z = (u32)f2bf((float)q1.x * sv) | ((u32)f2bf((float)q1.y * sv) << 16);
  pk.w = (u32)f2bf((float)q1.z * sv) | ((u32)f2bf((float)q1.w * sv) << 16);
  *reinterpret_cast<uint4*>(W + idx) = pk;
}

// ---------------------------------------------------------------------------
// Kernel 3: C[M][N] = A[M][K] @ B[N][K]^T + bias   (bf16 in, f32 out)
// m97 structure: 128x128 tile, BK=32, 4 waves, 4x4 16x16x32 MFMA per wave,
// global_load_lds width 16, linear LDS, bijective XCD swizzle.
// ---------------------------------------------------------------------------
__global__ __launch_bounds__(256)
void gemm_bt(const u16* __restrict__ A, const u16* __restrict__ B,
             const float* __restrict__ bias, float* __restrict__ C) {
  __shared__ __align__(16) u16 As[128 * 32];
  __shared__ __align__(16) u16 Bs[128 * 32];

  // XCD-aware bijective swizzle (grid = 2048, 2048 % 8 == 0)
  const int bid0 = blockIdx.x;
  const int bid  = (bid0 & 7) * (2048 >> 3) + (bid0 >> 3);
  const int mt = bid >> 5;   // 64 m-tiles
  const int nt = bid & 31;   // 32 n-tiles

  const int t    = threadIdx.x;
  const int wave = t >> 6;
  const int lane = t & 63;

  // staging: chunk c = t covers LDS bytes [c*16, c*16+16) of a [128][32] tile.
  // global source: tile row (t>>2), k-chunk (t&3)*8
  const size_t aOff0 = (size_t)(mt * 128 + (t >> 2)) * KDIM + (t & 3) * 8;
  const size_t aOff1 = aOff0 + (size_t)64 * KDIM;
  const size_t bOff0 = (size_t)(nt * 128 + (t >> 2)) * KDIM + (t & 3) * 8;
  const size_t bOff1 = bOff0 + (size_t)64 * KDIM;

  u16* AsW0 = &As[wave * 512];
  u16* AsW1 = &As[2048 + wave * 512];
  u16* BsW0 = &Bs[wave * 512];
  u16* BsW1 = &Bs[2048 + wave * 512];

  f32x4 acc[4][4];
#pragma unroll
  for (int m = 0; m < 4; ++m)
#pragma unroll
    for (int n = 0; n < 4; ++n)
      acc[m][n] = f32x4{0.f, 0.f, 0.f, 0.f};

  const int wm = wave >> 1, wn = wave & 1;
  const int rA = wm * 64 + (lane & 15);
  const int rB = wn * 64 + (lane & 15);
  const int kg = (lane >> 4) * 8;

  for (int k0 = 0; k0 < KDIM; k0 += 32) {
    __syncthreads();
    __builtin_amdgcn_global_load_lds(
        (const __attribute__((address_space(1))) void*)(A + aOff0 + k0),
        (__attribute__((address_space(3))) void*)AsW0, 16, 0, 0);
    __builtin_amdgcn_global_load_lds(
        (const __attribute__((address_space(1))) void*)(A + aOff1 + k0),
        (__attribute__((address_space(3))) void*)AsW1, 16, 0, 0);
    __builtin_amdgcn_global_load_lds(
        (const __attribute__((address_space(1))) void*)(B + bOff0 + k0),
        (__attribute__((address_space(3))) void*)BsW0, 16, 0, 0);
    __builtin_amdgcn_global_load_lds(
        (const __attribute__((address_space(1))) void*)(B + bOff1 + k0),
        (__attribute__((address_space(3))) void*)BsW1, 16, 0, 0);
    __syncthreads();

    bf16x8 af[4], bfr[4];
#pragma unroll
    for (int m = 0; m < 4; ++m)
      af[m] = *reinterpret_cast<const bf16x8*>(&As[(rA + m * 16) * 32 + kg]);
#pragma unroll
    for (int n = 0; n < 4; ++n)
      bfr[n] = *reinterpret_cast<const bf16x8*>(&Bs[(rB + n * 16) * 32 + kg]);
#pragma unroll
    for (int m = 0; m < 4; ++m)
#pragma unroll
      for (int n = 0; n < 4; ++n)
        acc[m][n] = __builtin_amdgcn_mfma_f32_16x16x32_bf16(af[m], bfr[n], acc[m][n], 0, 0, 0);
  }

  // epilogue: C[row][col] = acc + bias[col];  col = lane&15, row = (lane>>4)*4+reg
  const int colB = nt * 128 + wn * 64 + (lane & 15);
  const int rowB = mt * 128 + wm * 64 + ((lane >> 4) << 2);
#pragma unroll
  for (int n = 0; n < 4; ++n) {
    const float bv = bias[colB + n * 16];
#pragma unroll
    for (int m = 0; m < 4; ++m) {
#pragma unroll
      for (int r = 0; r < 4; ++r)
        C[(size_t)(rowB + m * 16 + r) * NDIM + (colB + n * 16)] = acc[m][n][r] + bv;
    }
  }
}

// ---------------------------------------------------------------------------
extern "C" void kernel_launch(void* const* d_in, const int* in_sizes, int n_in,
                              void* d_out, int out_size, void* d_ws, size_t ws_size,
                              hipStream_t stream) {
  (void)in_sizes; (void)n_in; (void)out_size; (void)ws_size;
  const float* x    = (const float*)d_in[0];
  const int*   Q    = (const int*)d_in[1];
  const float* s    = (const float*)d_in[2];
  const float* bias = (const float*)d_in[3];
  float* out = (float*)d_out;

  // workspace: xh bf16 [8192][4096] (64MB) + W bf16 [4096][4096] (32MB)
  u16* xh = (u16*)d_ws;
  u16* Wb = xh + (size_t)TOKENS * KDIM;

  fwht_rows<<<dim3(TOKENS), dim3(64), 0, stream>>>(x, xh);
  wconv<<<dim3((NDIM * KDIM) / (256 * 8)), dim3(256), 0, stream>>>(Q, s, Wb);
  gemm_bt<<<dim3((TOKENS / 128) * (NDIM / 128)), dim3(256), 0, stream>>>(xh, Wb, bias, out);
}

// Round 3
// 325.467 us; speedup vs baseline: 1.2209x; 1.2209x over previous
//
#include <hip/hip_runtime.h>
#include <hip/hip_bf16.h>

typedef float  f32x4  __attribute__((ext_vector_type(4)));
typedef short  bf16x8 __attribute__((ext_vector_type(8)));
typedef unsigned int   u32;
typedef unsigned short u16;

#define TOKENS 8192
#define NDIM   4096
#define KDIM   4096
#define BK     32
#define NKT    (KDIM / BK)   // 128 K-tiles

__device__ __forceinline__ u16 f2bf(float f) {
  u32 u = __float_as_uint(f);
  u += 0x7fffu + ((u >> 16) & 1u);   // round-to-nearest-even
  return (u16)(u >> 16);
}

// ---------------------------------------------------------------------------
// Kernel 1: FWHT over each row of x (4096 f32), orthonormal (scale 1/64),
// output bf16. One wave per row; 64 f32/lane; 6 in-reg + 6 shfl_xor stages.
// ---------------------------------------------------------------------------
__global__ __launch_bounds__(64)
void fwht_rows(const float* __restrict__ x, u16* __restrict__ xh) {
  const int row = blockIdx.x;
  const int l   = threadIdx.x;

  const float4* xv = reinterpret_cast<const float4*>(x + (size_t)row * KDIM) + l * 16;
  float v[64];
#pragma unroll
  for (int j = 0; j < 16; ++j) {
    float4 f = xv[j];
    v[4*j+0] = f.x; v[4*j+1] = f.y; v[4*j+2] = f.z; v[4*j+3] = f.w;
  }

#pragma unroll
  for (int h = 1; h < 64; h <<= 1) {
#pragma unroll
    for (int j = 0; j < 64; ++j) {
      if ((j & h) == 0) {
        float a = v[j], b = v[j + h];
        v[j] = a + b; v[j + h] = a - b;
      }
    }
  }

#pragma unroll
  for (int m = 1; m < 64; m <<= 1) {
    const bool up = (l & m) != 0;
#pragma unroll
    for (int j = 0; j < 64; ++j) {
      float p = __shfl_xor(v[j], m, 64);
      v[j] = up ? (p - v[j]) : (v[j] + p);
    }
  }

  u16* orow = xh + (size_t)row * KDIM + l * 64;
#pragma unroll
  for (int g = 0; g < 8; ++g) {
    uint4 pk;
    pk.x = (u32)f2bf(v[g*8+0] * 0.015625f) | ((u32)f2bf(v[g*8+1] * 0.015625f) << 16);
    pk.y = (u32)f2bf(v[g*8+2] * 0.015625f) | ((u32)f2bf(v[g*8+3] * 0.015625f) << 16);
    pk.z = (u32)f2bf(v[g*8+4] * 0.015625f) | ((u32)f2bf(v[g*8+5] * 0.015625f) << 16);
    pk.w = (u32)f2bf(v[g*8+6] * 0.015625f) | ((u32)f2bf(v[g*8+7] * 0.015625f) << 16);
    *reinterpret_cast<uint4*>(orow + g * 8) = pk;
  }
}

// ---------------------------------------------------------------------------
// Kernel 2: W[o][k] = bf16((float)Q[o][k] * s[o]).  8 elems/thread.
// ---------------------------------------------------------------------------
__global__ __launch_bounds__(256)
void wconv(const int* __restrict__ Q, const float* __restrict__ s,
           u16* __restrict__ W) {
  const size_t idx = ((size_t)blockIdx.x * 256 + threadIdx.x) * 8;
  const float sv = s[idx >> 12];
  int4 q0 = *reinterpret_cast<const int4*>(Q + idx);
  int4 q1 = *reinterpret_cast<const int4*>(Q + idx + 4);
  uint4 pk;
  pk.x = (u32)f2bf((float)q0.x * sv) | ((u32)f2bf((float)q0.y * sv) << 16);
  pk.y = (u32)f2bf((float)q0.z * sv) | ((u32)f2bf((float)q0.w * sv) << 16);
  pk.z = (u32)f2bf((float)q1.x * sv) | ((u32)f2bf((float)q1.y * sv) << 16);
  pk.w = (u32)f2bf((float)q1.z * sv) | ((u32)f2bf((float)q1.w * sv) << 16);
  *reinterpret_cast<uint4*>(W + idx) = pk;
}

// ---------------------------------------------------------------------------
// Kernel 3: C[M][N] = A[M][K] @ B[N][K]^T + bias   (bf16 in, f32 out)
// 256x256 tile, BK=32, 8 waves (2Mx4N), ring-4 LDS slots (128 KB),
// counted vmcnt(4) per K-tile (never 0 in steady state), raw s_barrier,
// st_16x32 XOR swizzle via pre-swizzled global source, setprio around MFMA.
//
// Slot layout (32768 bytes): A [256][32] bf16 at byte 0, B same at byte 16384.
// phys byte = row*64 + k*2, XOR'd by ((row>>3)&1)<<5.
// Schedule: while computing tile T (slot T%4), stage tile T+2 into slot
// (T+2)%4 (dead since tile T-2, >=3 barriers ago). vmcnt(4) at end of tile T
// guarantees tile T+1 landed (only T+2's 4 loads per wave still in flight).
// ---------------------------------------------------------------------------
__global__ __launch_bounds__(512, 2)
void gemm256(const u16* __restrict__ A, const u16* __restrict__ B,
             const float* __restrict__ bias, float* __restrict__ C) {
  __shared__ __align__(16) u16 lds[4 * 16384];   // 128 KB = 4 slots x (A 16KB + B 16KB)

  const int th   = threadIdx.x;
  const int wave = th >> 6;
  const int lane = th & 63;

  // bijective XCD swizzle (512 blocks, 512 % 8 == 0)
  const int b0  = blockIdx.x;
  const int bid = (b0 & 7) * 64 + (b0 >> 3);
  const int mt  = bid >> 4;   // 32 m-tiles
  const int nt  = bid & 15;   // 16 n-tiles

  // --- staging: thread th covers tile row (th>>2) [+128 for load 1],
  //     16B at pre-swizzled column (write-side XOR cancels read-side XOR)
  const int srow = th >> 2;
  const int scol = ((th & 3) * 8) ^ (((th >> 5) & 1) << 4);
  const u16* gA0 = A + (size_t)(mt * 256 + srow) * KDIM + scol;
  const u16* gA1 = gA0 + (size_t)128 * KDIM;
  const u16* gB0 = B + (size_t)(nt * 256 + srow) * KDIM + scol;
  const u16* gB1 = gB0 + (size_t)128 * KDIM;

  // wave-uniform LDS staging bases (u16 indices within a slot)
  const int ldsA0 = wave * 512;           // A rows wave*16..+16
  const int ldsA1 = 4096 + wave * 512;    // A rows 128+wave*16..+16
  const int ldsB0 = 8192 + wave * 512;    // B region starts at u16 8192 (byte 16384)
  const int ldsB1 = 12288 + wave * 512;

#define STAGE_A(tt, ss) do {                                                    \
    __builtin_amdgcn_global_load_lds(                                           \
      (const __attribute__((address_space(1))) void*)(gA0 + (size_t)(tt) * BK), \
      (__attribute__((address_space(3))) void*)(lds + (ss) * 16384 + ldsA0), 16, 0, 0); \
    __builtin_amdgcn_global_load_lds(                                           \
      (const __attribute__((address_space(1))) void*)(gA1 + (size_t)(tt) * BK), \
      (__attribute__((address_space(3))) void*)(lds + (ss) * 16384 + ldsA1), 16, 0, 0); \
  } while (0)
#define STAGE_B(tt, ss) do {                                                    \
    __builtin_amdgcn_global_load_lds(                                           \
      (const __attribute__((address_space(1))) void*)(gB0 + (size_t)(tt) * BK), \
      (__attribute__((address_space(3))) void*)(lds + (ss) * 16384 + ldsB0), 16, 0, 0); \
    __builtin_amdgcn_global_load_lds(                                           \
      (const __attribute__((address_space(1))) void*)(gB1 + (size_t)(tt) * BK), \
      (__attribute__((address_space(3))) void*)(lds + (ss) * 16384 + ldsB1), 16, 0, 0); \
  } while (0)

  // --- MFMA fragment read offsets (bytes within slot)
  const int wm = wave >> 2;       // 0..1  -> C rows wm*128..+128
  const int wn = wave & 3;        // 0..3  -> C cols wn*64..+64
  const int laneRow = lane & 15;
  const int kByte   = (lane >> 4) << 4;
  const int swz     = ((lane >> 3) & 1) << 5;
  const int aOff = (((wm * 128 + laneRow) * 64 + kByte) ^ swz);           // + mi*1024
  const int bOff = (((wn * 64 + laneRow) * 64 + kByte) ^ swz) + 16384;    // B at byte 16384

  f32x4 acc[8][4];
#pragma unroll
  for (int mi = 0; mi < 8; ++mi)
#pragma unroll
    for (int ni = 0; ni < 4; ++ni)
      acc[mi][ni] = f32x4{0.f, 0.f, 0.f, 0.f};

  // prologue: stage tiles 0,1 into slots 0,1; wait tile 0 (4 newest may fly)
  STAGE_A(0, 0); STAGE_B(0, 0);
  STAGE_A(1, 1); STAGE_B(1, 1);
  asm volatile("s_waitcnt vmcnt(4)" ::: "memory");
  __builtin_amdgcn_s_barrier();

  for (int t = 0; t < NKT; ++t) {
    const int slot = t & 3;
    const char* base = (const char*)lds + slot * 32768;

    bf16x8 bf[4], af[4];
    // ---- phase 1: read B (all ni) + A (mi 0..3); prefetch A of tile t+2
#pragma unroll
    for (int ni = 0; ni < 4; ++ni)
      bf[ni] = *(const bf16x8*)(base + bOff + ni * 1024);
#pragma unroll
    for (int mi = 0; mi < 4; ++mi)
      af[mi] = *(const bf16x8*)(base + aOff + mi * 1024);
    if (t + 2 < NKT) STAGE_A(t + 2, (t + 2) & 3);
    __builtin_amdgcn_s_barrier();
    __builtin_amdgcn_s_setprio(1);
#pragma unroll
    for (int mi = 0; mi < 4; ++mi)
#pragma unroll
      for (int ni = 0; ni < 4; ++ni)
        acc[mi][ni] = __builtin_amdgcn_mfma_f32_16x16x32_bf16(af[mi], bf[ni], acc[mi][ni], 0, 0, 0);
    __builtin_amdgcn_s_setprio(0);
    __builtin_amdgcn_s_barrier();

    // ---- phase 2: read A (mi 4..7); prefetch B of tile t+2
#pragma unroll
    for (int mi = 0; mi < 4; ++mi)
      af[mi] = *(const bf16x8*)(base + aOff + 4096 + mi * 1024);
    if (t + 2 < NKT) STAGE_B(t + 2, (t + 2) & 3);
    __builtin_amdgcn_s_barrier();
    __builtin_amdgcn_s_setprio(1);
#pragma unroll
    for (int mi = 0; mi < 4; ++mi)
#pragma unroll
      for (int ni = 0; ni < 4; ++ni)
        acc[mi + 4][ni] = __builtin_amdgcn_mfma_f32_16x16x32_bf16(af[mi], bf[ni], acc[mi + 4][ni], 0, 0, 0);
    __builtin_amdgcn_s_setprio(0);

    // counted drain: tile t+1 guaranteed landed; t+2's 4 loads stay in flight
    if (t + 2 < NKT)      asm volatile("s_waitcnt vmcnt(4)" ::: "memory");
    else if (t + 1 < NKT) asm volatile("s_waitcnt vmcnt(0)" ::: "memory");
    __builtin_amdgcn_s_barrier();
  }

  // epilogue: C[row][col] = acc + bias[col]; col = lane&15, row = (lane>>4)*4+r
  const int col0 = nt * 256 + wn * 64 + (lane & 15);
  const int row0 = mt * 256 + wm * 128 + ((lane >> 4) << 2);
#pragma unroll
  for (int ni = 0; ni < 4; ++ni) {
    const float bv = bias[col0 + ni * 16];
#pragma unroll
    for (int mi = 0; mi < 8; ++mi) {
      float* cp = C + (size_t)(row0 + mi * 16) * NDIM + col0 + ni * 16;
#pragma unroll
      for (int r = 0; r < 4; ++r)
        cp[(size_t)r * NDIM] = acc[mi][ni][r] + bv;
    }
  }
#undef STAGE_A
#undef STAGE_B
}

// ---------------------------------------------------------------------------
extern "C" void kernel_launch(void* const* d_in, const int* in_sizes, int n_in,
                              void* d_out, int out_size, void* d_ws, size_t ws_size,
                              hipStream_t stream) {
  (void)in_sizes; (void)n_in; (void)out_size; (void)ws_size;
  const float* x    = (const float*)d_in[0];
  const int*   Q    = (const int*)d_in[1];
  const float* s    = (const float*)d_in[2];
  const float* bias = (const float*)d_in[3];
  float* out = (float*)d_out;

  u16* xh = (u16*)d_ws;                       // bf16 [8192][4096]
  u16* Wb = xh + (size_t)TOKENS * KDIM;       // bf16 [4096][4096]

  fwht_rows<<<dim3(TOKENS), dim3(64), 0, stream>>>(x, xh);
  wconv<<<dim3((NDIM * KDIM) / (256 * 8)), dim3(256), 0, stream>>>(Q, s, Wb);
  gemm256<<<dim3((TOKENS / 256) * (NDIM / 256)), dim3(512), 0, stream>>>(xh, Wb, bias, out);
}

// Round 4
// 207.249 us; speedup vs baseline: 1.9173x; 1.5704x over previous
//
#include <hip/hip_runtime.h>
#include <hip/hip_bf16.h>

typedef int   i32x4 __attribute__((ext_vector_type(4)));
typedef unsigned int   u32;
typedef unsigned short u16;
typedef signed char    i8;

#define TOKENS 8192
#define NDIM   4096
#define KDIM   4096
#define BK     64            // K per tile, in i8 elements (= 64 bytes/row)
#define NKT    (KDIM / BK)   // 64 K-tiles

// ---------------------------------------------------------------------------
// Kernel 1: FWHT each row of x (4096 f32), then quantize the row to int8 with
// per-row scale = rowmax/127 (orthonormal 1/64 folded into the scale).
// One wave per row; 64 f32/lane; 6 in-reg + 6 shfl_xor butterfly stages.
// ---------------------------------------------------------------------------
__global__ __launch_bounds__(64)
void fwht_rows_q8(const float* __restrict__ x, i8* __restrict__ xq,
                  float* __restrict__ xscale) {
  const int row = blockIdx.x;
  const int l   = threadIdx.x;

  const float4* xv = reinterpret_cast<const float4*>(x + (size_t)row * KDIM) + l * 16;
  float v[64];
#pragma unroll
  for (int j = 0; j < 16; ++j) {
    float4 f = xv[j];
    v[4*j+0] = f.x; v[4*j+1] = f.y; v[4*j+2] = f.z; v[4*j+3] = f.w;
  }

#pragma unroll
  for (int h = 1; h < 64; h <<= 1) {
#pragma unroll
    for (int j = 0; j < 64; ++j) {
      if ((j & h) == 0) {
        float a = v[j], b = v[j + h];
        v[j] = a + b; v[j + h] = a - b;
      }
    }
  }

#pragma unroll
  for (int m = 1; m < 64; m <<= 1) {
    const bool up = (l & m) != 0;
#pragma unroll
    for (int j = 0; j < 64; ++j) {
      float p = __shfl_xor(v[j], m, 64);
      v[j] = up ? (p - v[j]) : (v[j] + p);
    }
  }

  // row absmax (unscaled), wave-reduce
  float mxu = 0.f;
#pragma unroll
  for (int j = 0; j < 64; ++j) mxu = fmaxf(mxu, fabsf(v[j]));
#pragma unroll
  for (int m = 1; m < 64; m <<= 1) mxu = fmaxf(mxu, __shfl_xor(mxu, m, 64));
  mxu = fmaxf(mxu, 1e-30f);
  const float inv = 127.0f / mxu;

  i8* orow = xq + (size_t)row * KDIM + l * 64;
#pragma unroll
  for (int g = 0; g < 4; ++g) {
    u32 w[4];
#pragma unroll
    for (int q4 = 0; q4 < 4; ++q4) {
      int b0 = __float2int_rn(v[g*16+q4*4+0] * inv);
      int b1 = __float2int_rn(v[g*16+q4*4+1] * inv);
      int b2 = __float2int_rn(v[g*16+q4*4+2] * inv);
      int b3 = __float2int_rn(v[g*16+q4*4+3] * inv);
      b0 = min(127, max(-127, b0)); b1 = min(127, max(-127, b1));
      b2 = min(127, max(-127, b2)); b3 = min(127, max(-127, b3));
      w[q4] = (u32)(b0 & 0xff) | ((u32)(b1 & 0xff) << 8) |
              ((u32)(b2 & 0xff) << 16) | ((u32)(b3 & 0xff) << 24);
    }
    uint4 pk; pk.x = w[0]; pk.y = w[1]; pk.z = w[2]; pk.w = w[3];
    *reinterpret_cast<uint4*>(orow + g * 16) = pk;
  }
  if (l == 0) xscale[row] = mxu * (0.015625f / 127.0f);  // (mx/64)/127
}

// ---------------------------------------------------------------------------
// Kernel 2: pack Q (int32, values in [-127,127]) to int8. 16 elems/thread.
// ---------------------------------------------------------------------------
__device__ __forceinline__ u32 pack4(int4 q) {
  return (u32)(q.x & 0xff) | ((u32)(q.y & 0xff) << 8) |
         ((u32)(q.z & 0xff) << 16) | ((u32)(q.w & 0xff) << 24);
}
__global__ __launch_bounds__(256)
void qpack(const int* __restrict__ Q, i8* __restrict__ W8) {
  const size_t idx = ((size_t)blockIdx.x * 256 + threadIdx.x) * 16;
  int4 a = *reinterpret_cast<const int4*>(Q + idx);
  int4 b = *reinterpret_cast<const int4*>(Q + idx + 4);
  int4 c = *reinterpret_cast<const int4*>(Q + idx + 8);
  int4 d = *reinterpret_cast<const int4*>(Q + idx + 12);
  uint4 pk; pk.x = pack4(a); pk.y = pack4(b); pk.z = pack4(c); pk.w = pack4(d);
  *reinterpret_cast<uint4*>(W8 + idx) = pk;
}

// ---------------------------------------------------------------------------
// Kernel 3: C[M][N] = dequant( Xq[M][K] @ W8[N][K]^T ) + bias
// int8 MFMA 16x16x64, i32 exact accumulation.
// Identical geometry to the validated bf16 ring-4 kernel: 256x256 tile,
// rows of 64 BYTES in LDS (now 64 i8 instead of 32 bf16), ring-4 slots
// (128 KB), same XOR swizzle (measured conflict-free), counted vmcnt(4),
// raw s_barrier, setprio around MFMA. BK=64 -> 64 K-tiles.
// Slot (32768 B): A [256 rows][64 B] at 0, B same at byte 16384.
// ---------------------------------------------------------------------------
__global__ __launch_bounds__(512, 2)
void gemm256_i8(const i8* __restrict__ A, const i8* __restrict__ B,
                const float* __restrict__ xscale, const float* __restrict__ s,
                const float* __restrict__ bias, float* __restrict__ C) {
  __shared__ __align__(16) i8 lds[4 * 32768];   // 128 KB

  const int th   = threadIdx.x;
  const int wave = th >> 6;
  const int lane = th & 63;

  // bijective XCD swizzle (512 blocks)
  const int b0  = blockIdx.x;
  const int bid = (b0 & 7) * 64 + (b0 >> 3);
  const int mt  = bid >> 4;   // 32 m-tiles
  const int nt  = bid & 15;   // 16 n-tiles

  // staging: thread th covers tile row (th>>2) [+128 for second load],
  // 16 B at pre-swizzled byte column (cancels the read-side XOR).
  const int srow = th >> 2;
  const int scol = ((th & 3) * 16) ^ (((th >> 5) & 1) << 5);
  const i8* gA0 = A + (size_t)(mt * 256 + srow) * KDIM + scol;
  const i8* gA1 = gA0 + (size_t)128 * KDIM;
  const i8* gB0 = B + (size_t)(nt * 256 + srow) * KDIM + scol;
  const i8* gB1 = gB0 + (size_t)128 * KDIM;

  // wave-uniform LDS staging bases (bytes within a slot)
  const int ldsA0 = wave * 1024;          // A rows 16w..16w+15
  const int ldsA1 = 8192 + wave * 1024;   // A rows 128+16w..
  const int ldsB0 = 16384 + wave * 1024;
  const int ldsB1 = 24576 + wave * 1024;

#define STAGE_A(tt, ss) do {                                                    \
    __builtin_amdgcn_global_load_lds(                                           \
      (const __attribute__((address_space(1))) void*)(gA0 + (size_t)(tt) * BK), \
      (__attribute__((address_space(3))) void*)(lds + (ss) * 32768 + ldsA0), 16, 0, 0); \
    __builtin_amdgcn_global_load_lds(                                           \
      (const __attribute__((address_space(1))) void*)(gA1 + (size_t)(tt) * BK), \
      (__attribute__((address_space(3))) void*)(lds + (ss) * 32768 + ldsA1), 16, 0, 0); \
  } while (0)
#define STAGE_B(tt, ss) do {                                                    \
    __builtin_amdgcn_global_load_lds(                                           \
      (const __attribute__((address_space(1))) void*)(gB0 + (size_t)(tt) * BK), \
      (__attribute__((address_space(3))) void*)(lds + (ss) * 32768 + ldsB0), 16, 0, 0); \
    __builtin_amdgcn_global_load_lds(                                           \
      (const __attribute__((address_space(1))) void*)(gB1 + (size_t)(tt) * BK), \
      (__attribute__((address_space(3))) void*)(lds + (ss) * 32768 + ldsB1), 16, 0, 0); \
  } while (0)

  // MFMA fragment byte offsets within slot: lane reads 16 B (16 i8, one
  // k-quarter of 64) at row = base + (lane&15), kByte = (lane>>4)*16,
  // XOR bit5 by row bit3 (same swizzle as staging).
  const int wm = wave >> 2;       // 0..1 -> C rows wm*128..+128
  const int wn = wave & 3;        // 0..3 -> C cols wn*64..+64
  const int laneRow = lane & 15;
  const int kByte   = (lane >> 4) << 4;
  const int swz     = ((lane >> 3) & 1) << 5;
  const int aOff = (((wm * 128 + laneRow) * 64 + kByte) ^ swz);          // + mi*1024
  const int bOff = (((wn * 64 + laneRow) * 64 + kByte) ^ swz) + 16384;   // + ni*1024

  i32x4 acc[8][4];
#pragma unroll
  for (int mi = 0; mi < 8; ++mi)
#pragma unroll
    for (int ni = 0; ni < 4; ++ni)
      acc[mi][ni] = i32x4{0, 0, 0, 0};

  // prologue: stage tiles 0,1 into slots 0,1; wait tile 0 (4 newest in flight)
  STAGE_A(0, 0); STAGE_B(0, 0);
  STAGE_A(1, 1); STAGE_B(1, 1);
  asm volatile("s_waitcnt vmcnt(4)" ::: "memory");
  __builtin_amdgcn_s_barrier();

  for (int t = 0; t < NKT; ++t) {
    const int slot = t & 3;
    const char* base = (const char*)lds + slot * 32768;

    i32x4 bfr[4], af[4];
    // ---- phase 1: read B (all ni) + A (mi 0..3); prefetch A of tile t+2
#pragma unroll
    for (int ni = 0; ni < 4; ++ni)
      bfr[ni] = *(const i32x4*)(base + bOff + ni * 1024);
#pragma unroll
    for (int mi = 0; mi < 4; ++mi)
      af[mi] = *(const i32x4*)(base + aOff + mi * 1024);
    if (t + 2 < NKT) STAGE_A(t + 2, (t + 2) & 3);
    __builtin_amdgcn_s_barrier();
    __builtin_amdgcn_s_setprio(1);
#pragma unroll
    for (int mi = 0; mi < 4; ++mi)
#pragma unroll
      for (int ni = 0; ni < 4; ++ni)
        acc[mi][ni] = __builtin_amdgcn_mfma_i32_16x16x64_i8(af[mi], bfr[ni], acc[mi][ni], 0, 0, 0);
    __builtin_amdgcn_s_setprio(0);
    __builtin_amdgcn_s_barrier();

    // ---- phase 2: read A (mi 4..7); prefetch B of tile t+2
#pragma unroll
    for (int mi = 0; mi < 4; ++mi)
      af[mi] = *(const i32x4*)(base + aOff + 4096 + mi * 1024);
    if (t + 2 < NKT) STAGE_B(t + 2, (t + 2) & 3);
    __builtin_amdgcn_s_barrier();
    __builtin_amdgcn_s_setprio(1);
#pragma unroll
    for (int mi = 0; mi < 4; ++mi)
#pragma unroll
      for (int ni = 0; ni < 4; ++ni)
        acc[mi + 4][ni] = __builtin_amdgcn_mfma_i32_16x16x64_i8(af[mi], bfr[ni], acc[mi + 4][ni], 0, 0, 0);
    __builtin_amdgcn_s_setprio(0);

    // counted drain: tile t+1 landed; t+2's 4 loads stay in flight
    if (t + 2 < NKT)      asm volatile("s_waitcnt vmcnt(4)" ::: "memory");
    else if (t + 1 < NKT) asm volatile("s_waitcnt vmcnt(0)" ::: "memory");
    __builtin_amdgcn_s_barrier();
  }

  // epilogue: y = acc * (xscale[row] * s[col]) + bias[col]
  // col = lane&15 (+ni*16), row = (lane>>4)*4 + r (+mi*16)
  const int col0 = nt * 256 + wn * 64 + (lane & 15);
  const int row0 = mt * 256 + wm * 128 + ((lane >> 4) << 2);
  float xs[4][8];   // xscale for rows row0 + mi*16 + r
#pragma unroll
  for (int mi = 0; mi < 8; ++mi)
#pragma unroll
    for (int r = 0; r < 4; ++r)
      xs[r][mi] = xscale[row0 + mi * 16 + r];
#pragma unroll
  for (int ni = 0; ni < 4; ++ni) {
    const float sc = s[col0 + ni * 16];
    const float bv = bias[col0 + ni * 16];
#pragma unroll
    for (int mi = 0; mi < 8; ++mi) {
      float* cp = C + (size_t)(row0 + mi * 16) * NDIM + col0 + ni * 16;
#pragma unroll
      for (int r = 0; r < 4; ++r)
        cp[(size_t)r * NDIM] = (float)acc[mi][ni][r] * (xs[r][mi] * sc) + bv;
    }
  }
#undef STAGE_A
#undef STAGE_B
}

// ---------------------------------------------------------------------------
extern "C" void kernel_launch(void* const* d_in, const int* in_sizes, int n_in,
                              void* d_out, int out_size, void* d_ws, size_t ws_size,
                              hipStream_t stream) {
  (void)in_sizes; (void)n_in; (void)out_size; (void)ws_size;
  const float* x    = (const float*)d_in[0];
  const int*   Q    = (const int*)d_in[1];
  const float* s    = (const float*)d_in[2];
  const float* bias = (const float*)d_in[3];
  float* out = (float*)d_out;

  i8*    xq     = (i8*)d_ws;                                 // [8192][4096] int8
  i8*    W8     = xq + (size_t)TOKENS * KDIM;                // [4096][4096] int8
  float* xscale = (float*)(W8 + (size_t)NDIM * KDIM);        // [8192] f32

  fwht_rows_q8<<<dim3(TOKENS), dim3(64), 0, stream>>>(x, xq, xscale);
  qpack<<<dim3((NDIM * KDIM) / (256 * 16)), dim3(256), 0, stream>>>(Q, W8);
  gemm256_i8<<<dim3((TOKENS / 256) * (NDIM / 256)), dim3(512), 0, stream>>>(
      xq, W8, xscale, s, bias, out);
}

// Round 5
// 204.766 us; speedup vs baseline: 1.9406x; 1.0121x over previous
//
#include <hip/hip_runtime.h>
#include <hip/hip_bf16.h>

typedef int   i32x4 __attribute__((ext_vector_type(4)));
typedef unsigned int   u32;
typedef unsigned short u16;
typedef signed char    i8;

#define TOKENS 8192
#define NDIM   4096
#define KDIM   4096
#define BK     64            // K per tile, in i8 elements (= 64 bytes/row)
#define NKT    (KDIM / BK)   // 64 K-tiles

// ---------------------------------------------------------------------------
// Kernel 1: FWHT each row of x (4096 f32), then quantize the row to int8 with
// per-row scale = rowmax/127 (orthonormal 1/64 folded into the scale).
// One wave per row; 64 f32/lane; 6 in-reg + 6 shfl_xor butterfly stages.
// ---------------------------------------------------------------------------
__global__ __launch_bounds__(64)
void fwht_rows_q8(const float* __restrict__ x, i8* __restrict__ xq,
                  float* __restrict__ xscale) {
  const int row = blockIdx.x;
  const int l   = threadIdx.x;

  const float4* xv = reinterpret_cast<const float4*>(x + (size_t)row * KDIM) + l * 16;
  float v[64];
#pragma unroll
  for (int j = 0; j < 16; ++j) {
    float4 f = xv[j];
    v[4*j+0] = f.x; v[4*j+1] = f.y; v[4*j+2] = f.z; v[4*j+3] = f.w;
  }

#pragma unroll
  for (int h = 1; h < 64; h <<= 1) {
#pragma unroll
    for (int j = 0; j < 64; ++j) {
      if ((j & h) == 0) {
        float a = v[j], b = v[j + h];
        v[j] = a + b; v[j + h] = a - b;
      }
    }
  }

#pragma unroll
  for (int m = 1; m < 64; m <<= 1) {
    const bool up = (l & m) != 0;
#pragma unroll
    for (int j = 0; j < 64; ++j) {
      float p = __shfl_xor(v[j], m, 64);
      v[j] = up ? (p - v[j]) : (v[j] + p);
    }
  }

  // row absmax (unscaled), wave-reduce
  float mxu = 0.f;
#pragma unroll
  for (int j = 0; j < 64; ++j) mxu = fmaxf(mxu, fabsf(v[j]));
#pragma unroll
  for (int m = 1; m < 64; m <<= 1) mxu = fmaxf(mxu, __shfl_xor(mxu, m, 64));
  mxu = fmaxf(mxu, 1e-30f);
  const float inv = 127.0f / mxu;

  i8* orow = xq + (size_t)row * KDIM + l * 64;
#pragma unroll
  for (int g = 0; g < 4; ++g) {
    u32 w[4];
#pragma unroll
    for (int q4 = 0; q4 < 4; ++q4) {
      int b0 = __float2int_rn(v[g*16+q4*4+0] * inv);
      int b1 = __float2int_rn(v[g*16+q4*4+1] * inv);
      int b2 = __float2int_rn(v[g*16+q4*4+2] * inv);
      int b3 = __float2int_rn(v[g*16+q4*4+3] * inv);
      b0 = min(127, max(-127, b0)); b1 = min(127, max(-127, b1));
      b2 = min(127, max(-127, b2)); b3 = min(127, max(-127, b3));
      w[q4] = (u32)(b0 & 0xff) | ((u32)(b1 & 0xff) << 8) |
              ((u32)(b2 & 0xff) << 16) | ((u32)(b3 & 0xff) << 24);
    }
    uint4 pk; pk.x = w[0]; pk.y = w[1]; pk.z = w[2]; pk.w = w[3];
    *reinterpret_cast<uint4*>(orow + g * 16) = pk;
  }
  if (l == 0) xscale[row] = mxu * (0.015625f / 127.0f);  // (mx/64)/127
}

// ---------------------------------------------------------------------------
// Kernel 2: pack Q (int32, values in [-127,127]) to int8. 16 elems/thread.
// ---------------------------------------------------------------------------
__device__ __forceinline__ u32 pack4(int4 q) {
  return (u32)(q.x & 0xff) | ((u32)(q.y & 0xff) << 8) |
         ((u32)(q.z & 0xff) << 16) | ((u32)(q.w & 0xff) << 24);
}
__global__ __launch_bounds__(256)
void qpack(const int* __restrict__ Q, i8* __restrict__ W8) {
  const size_t idx = ((size_t)blockIdx.x * 256 + threadIdx.x) * 16;
  int4 a = *reinterpret_cast<const int4*>(Q + idx);
  int4 b = *reinterpret_cast<const int4*>(Q + idx + 4);
  int4 c = *reinterpret_cast<const int4*>(Q + idx + 8);
  int4 d = *reinterpret_cast<const int4*>(Q + idx + 12);
  uint4 pk; pk.x = pack4(a); pk.y = pack4(b); pk.z = pack4(c); pk.w = pack4(d);
  *reinterpret_cast<uint4*>(W8 + idx) = pk;
}

// ---------------------------------------------------------------------------
// Kernel 3: C[M][N] = dequant( Xq[M][K] @ W8[N][K]^T ) + bias
// int8 MFMA 16x16x64, i32 exact accumulation. Validated ring-4 geometry
// (256x256 tile, 64B rows, XOR swizzle measured conflict-free, counted
// vmcnt(4), raw s_barrier, setprio).
//
// R5 change: L2-locality block mapping. XCD x (= b0&7) owns the 32mt x 2nt
// column stripe nt in {2x, 2x+1}, iterated mt-major. The ~32 concurrent
// blocks per XCD then share a 2 MB B panel (L2-resident, ~32x reuse) while
// 1 MB A panels stream from L3 (shared across all 8 XCDs at the same mt
// window). Expected: FETCH_SIZE 148 -> ~60 MB, gemm 155 -> 110-130 us.
// ---------------------------------------------------------------------------
__global__ __launch_bounds__(512, 2)
void gemm256_i8(const i8* __restrict__ A, const i8* __restrict__ B,
                const float* __restrict__ xscale, const float* __restrict__ s,
                const float* __restrict__ bias, float* __restrict__ C) {
  __shared__ __align__(16) i8 lds[4 * 32768];   // 128 KB

  const int th   = threadIdx.x;
  const int wave = th >> 6;
  const int lane = th & 63;

  // L2-locality mapping (bijective): XCD = b0&7 -> nt pair; mt-major within.
  const int b0 = blockIdx.x;
  const int xc = b0 & 7;
  const int i  = b0 >> 3;          // 0..63 sequence within XCD
  const int mt = i >> 1;           // 0..31
  const int nt = xc * 2 + (i & 1); // 0..15

  // staging: thread th covers tile row (th>>2) [+128 for second load],
  // 16 B at pre-swizzled byte column (cancels the read-side XOR).
  const int srow = th >> 2;
  const int scol = ((th & 3) * 16) ^ (((th >> 5) & 1) << 5);
  const i8* gA0 = A + (size_t)(mt * 256 + srow) * KDIM + scol;
  const i8* gA1 = gA0 + (size_t)128 * KDIM;
  const i8* gB0 = B + (size_t)(nt * 256 + srow) * KDIM + scol;
  const i8* gB1 = gB0 + (size_t)128 * KDIM;

  // wave-uniform LDS staging bases (bytes within a slot)
  const int ldsA0 = wave * 1024;          // A rows 16w..16w+15
  const int ldsA1 = 8192 + wave * 1024;   // A rows 128+16w..
  const int ldsB0 = 16384 + wave * 1024;
  const int ldsB1 = 24576 + wave * 1024;

#define STAGE_A(tt, ss) do {                                                    \
    __builtin_amdgcn_global_load_lds(                                           \
      (const __attribute__((address_space(1))) void*)(gA0 + (size_t)(tt) * BK), \
      (__attribute__((address_space(3))) void*)(lds + (ss) * 32768 + ldsA0), 16, 0, 0); \
    __builtin_amdgcn_global_load_lds(                                           \
      (const __attribute__((address_space(1))) void*)(gA1 + (size_t)(tt) * BK), \
      (__attribute__((address_space(3))) void*)(lds + (ss) * 32768 + ldsA1), 16, 0, 0); \
  } while (0)
#define STAGE_B(tt, ss) do {                                                    \
    __builtin_amdgcn_global_load_lds(                                           \
      (const __attribute__((address_space(1))) void*)(gB0 + (size_t)(tt) * BK), \
      (__attribute__((address_space(3))) void*)(lds + (ss) * 32768 + ldsB0), 16, 0, 0); \
    __builtin_amdgcn_global_load_lds(                                           \
      (const __attribute__((address_space(1))) void*)(gB1 + (size_t)(tt) * BK), \
      (__attribute__((address_space(3))) void*)(lds + (ss) * 32768 + ldsB1), 16, 0, 0); \
  } while (0)

  // MFMA fragment byte offsets within slot: lane reads 16 B at
  // row = base + (lane&15), kByte = (lane>>4)*16, XOR bit5 by row bit3.
  const int wm = wave >> 2;       // 0..1 -> C rows wm*128..+128
  const int wn = wave & 3;        // 0..3 -> C cols wn*64..+64
  const int laneRow = lane & 15;
  const int kByte   = (lane >> 4) << 4;
  const int swz     = ((lane >> 3) & 1) << 5;
  const int aOff = (((wm * 128 + laneRow) * 64 + kByte) ^ swz);          // + mi*1024
  const int bOff = (((wn * 64 + laneRow) * 64 + kByte) ^ swz) + 16384;   // + ni*1024

  i32x4 acc[8][4];
#pragma unroll
  for (int mi = 0; mi < 8; ++mi)
#pragma unroll
    for (int ni = 0; ni < 4; ++ni)
      acc[mi][ni] = i32x4{0, 0, 0, 0};

  // prologue: stage tiles 0,1 into slots 0,1; wait tile 0 (4 newest in flight)
  STAGE_A(0, 0); STAGE_B(0, 0);
  STAGE_A(1, 1); STAGE_B(1, 1);
  asm volatile("s_waitcnt vmcnt(4)" ::: "memory");
  __builtin_amdgcn_s_barrier();

  for (int t = 0; t < NKT; ++t) {
    const int slot = t & 3;
    const char* base = (const char*)lds + slot * 32768;

    i32x4 bfr[4], af[4];
    // ---- phase 1: read B (all ni) + A (mi 0..3); prefetch A of tile t+2
#pragma unroll
    for (int ni = 0; ni < 4; ++ni)
      bfr[ni] = *(const i32x4*)(base + bOff + ni * 1024);
#pragma unroll
    for (int mi = 0; mi < 4; ++mi)
      af[mi] = *(const i32x4*)(base + aOff + mi * 1024);
    if (t + 2 < NKT) STAGE_A(t + 2, (t + 2) & 3);
    __builtin_amdgcn_s_barrier();
    __builtin_amdgcn_s_setprio(1);
#pragma unroll
    for (int mi = 0; mi < 4; ++mi)
#pragma unroll
      for (int ni = 0; ni < 4; ++ni)
        acc[mi][ni] = __builtin_amdgcn_mfma_i32_16x16x64_i8(af[mi], bfr[ni], acc[mi][ni], 0, 0, 0);
    __builtin_amdgcn_s_setprio(0);
    __builtin_amdgcn_s_barrier();

    // ---- phase 2: read A (mi 4..7); prefetch B of tile t+2
#pragma unroll
    for (int mi = 0; mi < 4; ++mi)
      af[mi] = *(const i32x4*)(base + aOff + 4096 + mi * 1024);
    if (t + 2 < NKT) STAGE_B(t + 2, (t + 2) & 3);
    __builtin_amdgcn_s_barrier();
    __builtin_amdgcn_s_setprio(1);
#pragma unroll
    for (int mi = 0; mi < 4; ++mi)
#pragma unroll
      for (int ni = 0; ni < 4; ++ni)
        acc[mi + 4][ni] = __builtin_amdgcn_mfma_i32_16x16x64_i8(af[mi], bfr[ni], acc[mi + 4][ni], 0, 0, 0);
    __builtin_amdgcn_s_setprio(0);

    // counted drain: tile t+1 landed; t+2's 4 loads stay in flight
    if (t + 2 < NKT)      asm volatile("s_waitcnt vmcnt(4)" ::: "memory");
    else if (t + 1 < NKT) asm volatile("s_waitcnt vmcnt(0)" ::: "memory");
    __builtin_amdgcn_s_barrier();
  }

  // epilogue: y = acc * (xscale[row] * s[col]) + bias[col]
  // col = lane&15 (+ni*16), row = (lane>>4)*4 + r (+mi*16)
  const int col0 = nt * 256 + wn * 64 + (lane & 15);
  const int row0 = mt * 256 + wm * 128 + ((lane >> 4) << 2);
  float xs[4][8];   // xscale for rows row0 + mi*16 + r
#pragma unroll
  for (int mi = 0; mi < 8; ++mi)
#pragma unroll
    for (int r = 0; r < 4; ++r)
      xs[r][mi] = xscale[row0 + mi * 16 + r];
#pragma unroll
  for (int ni = 0; ni < 4; ++ni) {
    const float sc = s[col0 + ni * 16];
    const float bv = bias[col0 + ni * 16];
#pragma unroll
    for (int mi = 0; mi < 8; ++mi) {
      float* cp = C + (size_t)(row0 + mi * 16) * NDIM + col0 + ni * 16;
#pragma unroll
      for (int r = 0; r < 4; ++r)
        cp[(size_t)r * NDIM] = (float)acc[mi][ni][r] * (xs[r][mi] * sc) + bv;
    }
  }
#undef STAGE_A
#undef STAGE_B
}

// ---------------------------------------------------------------------------
extern "C" void kernel_launch(void* const* d_in, const int* in_sizes, int n_in,
                              void* d_out, int out_size, void* d_ws, size_t ws_size,
                              hipStream_t stream) {
  (void)in_sizes; (void)n_in; (void)out_size; (void)ws_size;
  const float* x    = (const float*)d_in[0];
  const int*   Q    = (const int*)d_in[1];
  const float* s    = (const float*)d_in[2];
  const float* bias = (const float*)d_in[3];
  float* out = (float*)d_out;

  i8*    xq     = (i8*)d_ws;                                 // [8192][4096] int8
  i8*    W8     = xq + (size_t)TOKENS * KDIM;                // [4096][4096] int8
  float* xscale = (float*)(W8 + (size_t)NDIM * KDIM);        // [8192] f32

  fwht_rows_q8<<<dim3(TOKENS), dim3(64), 0, stream>>>(x, xq, xscale);
  qpack<<<dim3((NDIM * KDIM) / (256 * 16)), dim3(256), 0, stream>>>(Q, W8);
  gemm256_i8<<<dim3((TOKENS / 256) * (NDIM / 256)), dim3(512), 0, stream>>>(
      xq, W8, xscale, s, bias, out);
}

// Round 6
// 204.694 us; speedup vs baseline: 1.9412x; 1.0004x over previous
//
#include <hip/hip_runtime.h>
#include <hip/hip_bf16.h>

typedef int   i32x4 __attribute__((ext_vector_type(4)));
typedef unsigned int   u32;
typedef unsigned short u16;
typedef signed char    i8;

#define TOKENS 8192
#define NDIM   4096
#define KDIM   4096
#define BK     64            // K per tile, in i8 elements (= 64 bytes/row)
#define NKT    (KDIM / BK)   // 64 K-tiles

// ---------------------------------------------------------------------------
// Kernel 1: FWHT each row of x (4096 f32), quantize row to int8, per-row scale.
// ---------------------------------------------------------------------------
__global__ __launch_bounds__(64)
void fwht_rows_q8(const float* __restrict__ x, i8* __restrict__ xq,
                  float* __restrict__ xscale) {
  const int row = blockIdx.x;
  const int l   = threadIdx.x;

  const float4* xv = reinterpret_cast<const float4*>(x + (size_t)row * KDIM) + l * 16;
  float v[64];
#pragma unroll
  for (int j = 0; j < 16; ++j) {
    float4 f = xv[j];
    v[4*j+0] = f.x; v[4*j+1] = f.y; v[4*j+2] = f.z; v[4*j+3] = f.w;
  }

#pragma unroll
  for (int h = 1; h < 64; h <<= 1) {
#pragma unroll
    for (int j = 0; j < 64; ++j) {
      if ((j & h) == 0) {
        float a = v[j], b = v[j + h];
        v[j] = a + b; v[j + h] = a - b;
      }
    }
  }

#pragma unroll
  for (int m = 1; m < 64; m <<= 1) {
    const bool up = (l & m) != 0;
#pragma unroll
    for (int j = 0; j < 64; ++j) {
      float p = __shfl_xor(v[j], m, 64);
      v[j] = up ? (p - v[j]) : (v[j] + p);
    }
  }

  float mxu = 0.f;
#pragma unroll
  for (int j = 0; j < 64; ++j) mxu = fmaxf(mxu, fabsf(v[j]));
#pragma unroll
  for (int m = 1; m < 64; m <<= 1) mxu = fmaxf(mxu, __shfl_xor(mxu, m, 64));
  mxu = fmaxf(mxu, 1e-30f);
  const float inv = 127.0f / mxu;

  i8* orow = xq + (size_t)row * KDIM + l * 64;
#pragma unroll
  for (int g = 0; g < 4; ++g) {
    u32 w[4];
#pragma unroll
    for (int q4 = 0; q4 < 4; ++q4) {
      int b0 = __float2int_rn(v[g*16+q4*4+0] * inv);
      int b1 = __float2int_rn(v[g*16+q4*4+1] * inv);
      int b2 = __float2int_rn(v[g*16+q4*4+2] * inv);
      int b3 = __float2int_rn(v[g*16+q4*4+3] * inv);
      b0 = min(127, max(-127, b0)); b1 = min(127, max(-127, b1));
      b2 = min(127, max(-127, b2)); b3 = min(127, max(-127, b3));
      w[q4] = (u32)(b0 & 0xff) | ((u32)(b1 & 0xff) << 8) |
              ((u32)(b2 & 0xff) << 16) | ((u32)(b3 & 0xff) << 24);
    }
    uint4 pk; pk.x = w[0]; pk.y = w[1]; pk.z = w[2]; pk.w = w[3];
    *reinterpret_cast<uint4*>(orow + g * 16) = pk;
  }
  if (l == 0) xscale[row] = mxu * (0.015625f / 127.0f);  // (mx/64)/127
}

// ---------------------------------------------------------------------------
// Kernel 2: pack Q (int32 in [-127,127]) to int8. 16 elems/thread.
// ---------------------------------------------------------------------------
__device__ __forceinline__ u32 pack4(int4 q) {
  return (u32)(q.x & 0xff) | ((u32)(q.y & 0xff) << 8) |
         ((u32)(q.z & 0xff) << 16) | ((u32)(q.w & 0xff) << 24);
}
__global__ __launch_bounds__(256)
void qpack(const int* __restrict__ Q, i8* __restrict__ W8) {
  const size_t idx = ((size_t)blockIdx.x * 256 + threadIdx.x) * 16;
  int4 a = *reinterpret_cast<const int4*>(Q + idx);
  int4 b = *reinterpret_cast<const int4*>(Q + idx + 4);
  int4 c = *reinterpret_cast<const int4*>(Q + idx + 8);
  int4 d = *reinterpret_cast<const int4*>(Q + idx + 12);
  uint4 pk; pk.x = pack4(a); pk.y = pack4(b); pk.z = pack4(c); pk.w = pack4(d);
  *reinterpret_cast<uint4*>(W8 + idx) = pk;
}

// ---------------------------------------------------------------------------
// Kernel 3: int8 GEMM, register-level software pipeline.
// 256x256 tile, BK=64, 8 waves, ring-4 slots (128 KB, 1 block/CU by design).
// Per K-tile: ONE barrier; ds_reads for the NEXT MFMA section issued under
// the CURRENT section's MFMA; counted lgkmcnt(4/8) (never 0 mid-loop);
// per-wave vmcnt(2) + barrier orders staging vs reads. bf sets ping-ponged
// via 2x unroll (no runtime-indexed register arrays).
// ---------------------------------------------------------------------------
__global__ __launch_bounds__(512, 2)
void gemm256_i8(const i8* __restrict__ A, const i8* __restrict__ B,
                const float* __restrict__ xscale, const float* __restrict__ s,
                const float* __restrict__ bias, float* __restrict__ C) {
  __shared__ __align__(16) i8 lds[4 * 32768];   // 128 KB

  const int th   = threadIdx.x;
  const int wave = th >> 6;
  const int lane = th & 63;

  // L2-locality mapping (kept from R5; bijective)
  const int b0 = blockIdx.x;
  const int xc = b0 & 7;
  const int i  = b0 >> 3;
  const int mt = i >> 1;
  const int nt = xc * 2 + (i & 1);

  const int srow = th >> 2;
  const int scol = ((th & 3) * 16) ^ (((th >> 5) & 1) << 5);
  const i8* gA0 = A + (size_t)(mt * 256 + srow) * KDIM + scol;
  const i8* gA1 = gA0 + (size_t)128 * KDIM;
  const i8* gB0 = B + (size_t)(nt * 256 + srow) * KDIM + scol;
  const i8* gB1 = gB0 + (size_t)128 * KDIM;

  const int ldsA0 = wave * 1024;
  const int ldsA1 = 8192 + wave * 1024;
  const int ldsB0 = 16384 + wave * 1024;
  const int ldsB1 = 24576 + wave * 1024;

#define STAGE_A(tt, ss) do {                                                    \
    __builtin_amdgcn_global_load_lds(                                           \
      (const __attribute__((address_space(1))) void*)(gA0 + (size_t)(tt) * BK), \
      (__attribute__((address_space(3))) void*)(lds + (ss) * 32768 + ldsA0), 16, 0, 0); \
    __builtin_amdgcn_global_load_lds(                                           \
      (const __attribute__((address_space(1))) void*)(gA1 + (size_t)(tt) * BK), \
      (__attribute__((address_space(3))) void*)(lds + (ss) * 32768 + ldsA1), 16, 0, 0); \
  } while (0)
#define STAGE_B(tt, ss) do {                                                    \
    __builtin_amdgcn_global_load_lds(                                           \
      (const __attribute__((address_space(1))) void*)(gB0 + (size_t)(tt) * BK), \
      (__attribute__((address_space(3))) void*)(lds + (ss) * 32768 + ldsB0), 16, 0, 0); \
    __builtin_amdgcn_global_load_lds(                                           \
      (const __attribute__((address_space(1))) void*)(gB1 + (size_t)(tt) * BK), \
      (__attribute__((address_space(3))) void*)(lds + (ss) * 32768 + ldsB1), 16, 0, 0); \
  } while (0)

  const int wm = wave >> 2;
  const int wn = wave & 3;
  const int laneRow = lane & 15;
  const int kByte   = (lane >> 4) << 4;
  const int swz     = ((lane >> 3) & 1) << 5;
  const int aOff = (((wm * 128 + laneRow) * 64 + kByte) ^ swz);
  const int bOff = (((wn * 64 + laneRow) * 64 + kByte) ^ swz) + 16384;

  i32x4 acc[8][4];
#pragma unroll
  for (int mi = 0; mi < 8; ++mi)
#pragma unroll
    for (int ni = 0; ni < 4; ++ni)
      acc[mi][ni] = i32x4{0, 0, 0, 0};

  // prologue: stage tiles 0,1; wait tile 0; barrier; preload tile-0 operands
  STAGE_A(0, 0); STAGE_B(0, 0);
  STAGE_A(1, 1); STAGE_B(1, 1);
  asm volatile("s_waitcnt vmcnt(4)" ::: "memory");
  __builtin_amdgcn_sched_barrier(0);
  __builtin_amdgcn_s_barrier();

  i32x4 afA[4], afB[4], bf0[4], bf1[4];
  {
    const char* c0 = (const char*)lds;   // slot 0
#pragma unroll
    for (int ni = 0; ni < 4; ++ni)
      bf0[ni] = *(const i32x4*)(c0 + bOff + ni * 1024);
#pragma unroll
    for (int mi = 0; mi < 4; ++mi)
      afA[mi] = *(const i32x4*)(c0 + aOff + mi * 1024);
  }

  // TILE body: BFC = this tile's B frags, BFN = next tile's (loaded here).
#define TILE(t, BFC, BFN) do {                                                  \
    const char* cur = (const char*)lds + ((t) & 3) * 32768;                     \
    const char* nxt = (const char*)lds + (((t) + 1) & 3) * 32768;               \
    /* issue half-1 A reads (fly under half-0 MFMA) */                          \
    _Pragma("unroll")                                                           \
    for (int mi = 0; mi < 4; ++mi)                                              \
      afB[mi] = *(const i32x4*)(cur + aOff + 4096 + mi * 1024);                 \
    if ((t) + 2 < NKT) STAGE_A((t) + 2, ((t) + 2) & 3);                         \
    asm volatile("s_waitcnt lgkmcnt(4)" ::: "memory");  /* afA,BFC ready */     \
    __builtin_amdgcn_sched_barrier(0);                                          \
    __builtin_amdgcn_s_setprio(1);                                              \
    _Pragma("unroll")                                                           \
    for (int mi = 0; mi < 4; ++mi)                                              \
      _Pragma("unroll")                                                         \
      for (int ni = 0; ni < 4; ++ni)                                            \
        acc[mi][ni] = __builtin_amdgcn_mfma_i32_16x16x64_i8(afA[mi], BFC[ni],   \
                                                            acc[mi][ni], 0, 0, 0); \
    __builtin_amdgcn_s_setprio(0);                                              \
    if ((t) + 1 < NKT) {                                                        \
      if ((t) + 2 < NKT) { asm volatile("s_waitcnt vmcnt(2)" ::: "memory"); }   \
      else               { asm volatile("s_waitcnt vmcnt(0)" ::: "memory"); }   \
      __builtin_amdgcn_sched_barrier(0);                                        \
      __builtin_amdgcn_s_barrier();   /* tile t+1 staged for ALL waves */       \
      _Pragma("unroll")                                                         \
      for (int ni = 0; ni < 4; ++ni)                                            \
        BFN[ni] = *(const i32x4*)(nxt + bOff + ni * 1024);                      \
      _Pragma("unroll")                                                         \
      for (int mi = 0; mi < 4; ++mi)                                            \
        afA[mi] = *(const i32x4*)(nxt + aOff + mi * 1024);                      \
      if ((t) + 2 < NKT) STAGE_B((t) + 2, ((t) + 2) & 3);                       \
      asm volatile("s_waitcnt lgkmcnt(8)" ::: "memory");  /* afB ready */       \
      __builtin_amdgcn_sched_barrier(0);                                        \
    } else {                                                                    \
      asm volatile("s_waitcnt lgkmcnt(0)" ::: "memory");                        \
      __builtin_amdgcn_sched_barrier(0);                                        \
    }                                                                           \
    __builtin_amdgcn_s_setprio(1);                                              \
    _Pragma("unroll")                                                           \
    for (int mi = 0; mi < 4; ++mi)                                              \
      _Pragma("unroll")                                                         \
      for (int ni = 0; ni < 4; ++ni)                                            \
        acc[mi + 4][ni] = __builtin_amdgcn_mfma_i32_16x16x64_i8(afB[mi], BFC[ni], \
                                                            acc[mi + 4][ni], 0, 0, 0); \
    __builtin_amdgcn_s_setprio(0);                                              \
  } while (0)

  for (int t = 0; t < NKT; t += 2) {
    TILE(t,     bf0, bf1);
    TILE(t + 1, bf1, bf0);
  }
#undef TILE
#undef STAGE_A
#undef STAGE_B

  // epilogue: y = acc * (xscale[row] * s[col]) + bias[col]
  const int col0 = nt * 256 + wn * 64 + (lane & 15);
  const int row0 = mt * 256 + wm * 128 + ((lane >> 4) << 2);
  float xs[4][8];
#pragma unroll
  for (int mi = 0; mi < 8; ++mi)
#pragma unroll
    for (int r = 0; r < 4; ++r)
      xs[r][mi] = xscale[row0 + mi * 16 + r];
#pragma unroll
  for (int ni = 0; ni < 4; ++ni) {
    const float sc = s[col0 + ni * 16];
    const float bv = bias[col0 + ni * 16];
#pragma unroll
    for (int mi = 0; mi < 8; ++mi) {
      float* cp = C + (size_t)(row0 + mi * 16) * NDIM + col0 + ni * 16;
#pragma unroll
      for (int r = 0; r < 4; ++r)
        cp[(size_t)r * NDIM] = (float)acc[mi][ni][r] * (xs[r][mi] * sc) + bv;
    }
  }
}

// ---------------------------------------------------------------------------
extern "C" void kernel_launch(void* const* d_in, const int* in_sizes, int n_in,
                              void* d_out, int out_size, void* d_ws, size_t ws_size,
                              hipStream_t stream) {
  (void)in_sizes; (void)n_in; (void)out_size; (void)ws_size;
  const float* x    = (const float*)d_in[0];
  const int*   Q    = (const int*)d_in[1];
  const float* s    = (const float*)d_in[2];
  const float* bias = (const float*)d_in[3];
  float* out = (float*)d_out;

  i8*    xq     = (i8*)d_ws;
  i8*    W8     = xq + (size_t)TOKENS * KDIM;
  float* xscale = (float*)(W8 + (size_t)NDIM * KDIM);

  fwht_rows_q8<<<dim3(TOKENS), dim3(64), 0, stream>>>(x, xq, xscale);
  qpack<<<dim3((NDIM * KDIM) / (256 * 16)), dim3(256), 0, stream>>>(Q, W8);
  gemm256_i8<<<dim3((TOKENS / 256) * (NDIM / 256)), dim3(512), 0, stream>>>(
      xq, W8, xscale, s, bias, out);
}